// Round 1
// baseline (338.444 us; speedup 1.0000x reference)
//
#include <hip/hip_runtime.h>

// ---------- types ----------
typedef __bf16 bf16x8 __attribute__((ext_vector_type(8)));
typedef float  f32x4  __attribute__((ext_vector_type(4)));

#define IN_CH  256
#define OUT_CH 256
#define HIDDEN 2048
#define NB     8
#define NT     4000
#define NROW   32000   // NB*NT

__device__ __forceinline__ unsigned short f2bf(float f) {
    unsigned u = __float_as_uint(f);
    u += 0x7FFFu + ((u >> 16) & 1u);           // round-to-nearest-even
    return (unsigned short)(u >> 16);
}
__device__ __forceinline__ float bf2f(unsigned short h) {
    return __uint_as_float(((unsigned)h) << 16);
}

// ---------- 1. fp32 -> bf16 convert (weights) ----------
__global__ void cvt_kernel(const float* __restrict__ in,
                           unsigned short* __restrict__ out, int n4) {
    int i = blockIdx.x * blockDim.x + threadIdx.x;
    if (i >= n4) return;
    float4 v = reinterpret_cast<const float4*>(in)[i];
    ushort4 o;
    o.x = f2bf(v.x); o.y = f2bf(v.y); o.z = f2bf(v.z); o.w = f2bf(v.w);
    reinterpret_cast<ushort4*>(out)[i] = o;
}

// ---------- 2. partial mean/var reduction over T ----------
// grid 256 = 8 batches x 32 t-chunks (125 rows each); 256 threads = channels
__global__ void reduce_kernel(const float* __restrict__ x,
                              float* __restrict__ psum, float* __restrict__ psq) {
    int c = threadIdx.x;
    int blk = blockIdx.x;
    int b = blk >> 5, tc = blk & 31;
    const float* base = x + ((size_t)b * NT + tc * 125) * IN_CH + c;
    float s = 0.f, q = 0.f;
    for (int t = 0; t < 125; ++t) {
        float v = base[(size_t)t * IN_CH];
        s += v; q += v * v;
    }
    psum[blk * IN_CH + c] = s;
    psq [blk * IN_CH + c] = q;
}

// ---------- 3. gate: mean/std -> logits -> probs -> losses ----------
__global__ __launch_bounds__(256) void gate_kernel(
    const float* __restrict__ psum, const float* __restrict__ psq,
    const float* __restrict__ gate_w, const float* __restrict__ gate_b,
    const float* __restrict__ tau, float* __restrict__ probs,
    float* __restrict__ losses) {
    __shared__ float gi[NB][2 * IN_CH];
    __shared__ float lgt[16];
    int tid = threadIdx.x;
    for (int b = 0; b < NB; ++b) {
        float s = 0.f, q = 0.f;
        for (int p = 0; p < 32; ++p) {
            s += psum[(b * 32 + p) * IN_CH + tid];
            q += psq [(b * 32 + p) * IN_CH + tid];
        }
        float mean = s * (1.f / 4000.f);
        float var  = (q - s * s * (1.f / 4000.f)) * (1.f / 3999.f);  // ddof=1
        gi[b][tid]          = mean;
        gi[b][IN_CH + tid]  = sqrtf(fmaxf(var, 0.f));
    }
    __syncthreads();
    if (tid < 16) {
        int b = tid >> 1, k = tid & 1;
        float d = 0.f;
        for (int i = 0; i < 2 * IN_CH; ++i) d += gi[b][i] * gate_w[k * 2 * IN_CH + i];
        lgt[tid] = tau[0] * (d + gate_b[k]);
    }
    __syncthreads();
    if (tid == 0) {
        float pr[16];
        float i0 = 0.f, i1 = 0.f, sp = 0.f;
        for (int b = 0; b < NB; ++b) {
            float a = lgt[b * 2], c2 = lgt[b * 2 + 1];
            float mx = fmaxf(a, c2);
            float e0 = expf(a - mx), e1 = expf(c2 - mx);
            float inv = 1.f / (e0 + e1);
            float q0 = e0 * inv, q1 = e1 * inv;
            pr[b * 2] = q0; pr[b * 2 + 1] = q1;
            i0 += q0; i1 += q1;
            float nrm = sqrtf(q0 * q0 + q1 * q1) + 1e-8f;
            sp += (q0 + q1) / nrm;           // probs >= 0 so |.| = value
        }
        losses[0] = 0.1f * sp * (1.f / 8.f);           // sparsity_loss
        i0 *= (1.f / 8.f); i1 *= (1.f / 8.f);
        float meanI = 0.5f * (i0 + i1);
        float stdI  = fabsf(i0 - i1) * 0.7071067811865476f;  // ddof=1, n=2
        float cv = stdI / (meanI + 1e-8f);
        losses[1] = 0.01f * cv * cv;                   // importance_loss
        for (int t = 0; t < 16; ++t) probs[t] = pr[t];
    }
}

// ---------- 4. fused GEMM1(relu)+GEMM2 with mid-loop small snapshot ----------
// 500 blocks x 512 threads (8 waves). Tile: 64 rows, full 256 out cols.
// Hidden processed in 32 chunks of 64. After chunk 3 (= hidden 0..255) the
// accumulators equal p1_small -> stored. Final accumulators = p1_full.
__global__ __launch_bounds__(512, 2) void gemm_kernel(
    const float* __restrict__ x,
    const unsigned short* __restrict__ w1b,   // [2048][256] bf16
    const unsigned short* __restrict__ w2b,   // [256][2048] bf16
    const float* __restrict__ b1,
    unsigned short* __restrict__ msmall,      // [32000][256] bf16
    unsigned short* __restrict__ mfull) {
    __shared__ __align__(16) unsigned short xt [64 * 256];  // swizzled
    __shared__ __align__(16) unsigned short w1c[64 * 256];  // swizzled
    __shared__ __align__(16) unsigned short w2c[256 * 64];  // swizzled
    __shared__ __align__(16) unsigned short f1t[64 * 72];   // padded ld=72

    const int tid   = threadIdx.x;
    const int lane  = tid & 63;
    const int wv    = tid >> 6;       // 0..7
    const int rband = wv & 3;         // 16-row band
    const int chalf = wv >> 2;        // output col half (128 each)
    const int m0    = blockIdx.x * 64;
    const int l15   = lane & 15;
    const int lg    = lane >> 4;      // 0..3

    // stage x tile once: [64][256] fp32 -> bf16, XOR-swizzled rows
#pragma unroll
    for (int p = 0; p < 8; ++p) {
        int E = p * 2048 + tid * 4;
        int r = E >> 8, c = E & 255;
        float4 v = *reinterpret_cast<const float4*>(x + (size_t)(m0 + r) * IN_CH + c);
        ushort4 h;
        h.x = f2bf(v.x); h.y = f2bf(v.y); h.z = f2bf(v.z); h.w = f2bf(v.w);
        *reinterpret_cast<ushort4*>(&xt[r * 256 + (c ^ ((r & 7) << 3))]) = h;
    }

    f32x4 acc2[8];
#pragma unroll
    for (int t = 0; t < 8; ++t) { acc2[t][0]=0.f; acc2[t][1]=0.f; acc2[t][2]=0.f; acc2[t][3]=0.f; }

    const int arow = rband * 16 + l15;

#pragma unroll 1
    for (int chunk = 0; chunk < 32; ++chunk) {
        const int h0 = chunk * 64;
        // stage w1 chunk [64][256]
#pragma unroll
        for (int p = 0; p < 4; ++p) {
            int E = p * 4096 + tid * 8;
            int r = E >> 8, c = E & 255;
            int4 v = *reinterpret_cast<const int4*>(w1b + (size_t)(h0 + r) * IN_CH + c);
            *reinterpret_cast<int4*>(&w1c[r * 256 + (c ^ ((r & 7) << 3))]) = v;
        }
        // stage w2 chunk [256][64]
#pragma unroll
        for (int p = 0; p < 4; ++p) {
            int E = p * 4096 + tid * 8;
            int r = E >> 6, c = E & 63;
            int4 v = *reinterpret_cast<const int4*>(w2b + (size_t)r * HIDDEN + h0 + c);
            *reinterpret_cast<int4*>(&w2c[r * 64 + (c ^ ((r & 7) << 3))]) = v;
        }
        __syncthreads();

        // GEMM1: f1[band rows][chalf*32 .. +31] = relu(x @ w1'.T + b1)
        f32x4 acc1[2];
#pragma unroll
        for (int t = 0; t < 2; ++t) { acc1[t][0]=0.f; acc1[t][1]=0.f; acc1[t][2]=0.f; acc1[t][3]=0.f; }
#pragma unroll
        for (int kk = 0; kk < 8; ++kk) {
            int acol = kk * 32 + lg * 8;
            bf16x8 a = *reinterpret_cast<const bf16x8*>(
                &xt[arow * 256 + (acol ^ ((arow & 7) << 3))]);
#pragma unroll
            for (int t = 0; t < 2; ++t) {
                int hl = chalf * 32 + t * 16 + l15;
                bf16x8 bb = *reinterpret_cast<const bf16x8*>(
                    &w1c[hl * 256 + (acol ^ ((hl & 7) << 3))]);
                acc1[t] = __builtin_amdgcn_mfma_f32_16x16x32_bf16(a, bb, acc1[t], 0, 0, 0);
            }
        }
        // bias + relu + write f1 to LDS (padded)
#pragma unroll
        for (int t = 0; t < 2; ++t) {
            int hl = chalf * 32 + t * 16 + l15;
            float bias = b1[h0 + hl];
#pragma unroll
            for (int r = 0; r < 4; ++r) {
                float v = fmaxf(acc1[t][r] + bias, 0.f);
                int rr = rband * 16 + lg * 4 + r;
                f1t[rr * 72 + hl] = f2bf(v);
            }
        }
        __syncthreads();

        // GEMM2: acc2 += f1 @ w2_chunk.T
#pragma unroll
        for (int kk = 0; kk < 2; ++kk) {
            int kE = kk * 32 + lg * 8;
            bf16x8 a2 = *reinterpret_cast<const bf16x8*>(&f1t[arow * 72 + kE]);
#pragma unroll
            for (int t = 0; t < 8; ++t) {
                int oc = chalf * 128 + t * 16 + l15;
                bf16x8 b2 = *reinterpret_cast<const bf16x8*>(
                    &w2c[oc * 64 + (kE ^ ((oc & 7) << 3))]);
                acc2[t] = __builtin_amdgcn_mfma_f32_16x16x32_bf16(a2, b2, acc2[t], 0, 0, 0);
            }
        }

        if (chunk == 3) {   // hidden 0..255 done -> p1_small snapshot
#pragma unroll
            for (int t = 0; t < 8; ++t) {
                int oc = chalf * 128 + t * 16 + l15;
#pragma unroll
                for (int r = 0; r < 4; ++r) {
                    int rr = m0 + rband * 16 + lg * 4 + r;
                    msmall[(size_t)rr * OUT_CH + oc] = f2bf(acc2[t][r]);
                }
            }
        }
        __syncthreads();
    }
    // final: p1_full
#pragma unroll
    for (int t = 0; t < 8; ++t) {
        int oc = chalf * 128 + t * 16 + l15;
#pragma unroll
        for (int r = 0; r < 4; ++r) {
            int rr = m0 + rband * 16 + lg * 4 + r;
            mfull[(size_t)rr * OUT_CH + oc] = f2bf(acc2[t][r]);
        }
    }
}

// ---------- 5. mix + depthwise conv (39 taps) + identity ----------
// grid 2000 = 8 b x 250 t-tiles (16 t each); 256 threads = channels
__global__ __launch_bounds__(256) void conv_kernel(
    const unsigned short* __restrict__ msmall,
    const unsigned short* __restrict__ mfull,
    const float* __restrict__ conv_w,   // [256][1][39]
    const float* __restrict__ probs,    // [8][2]
    float* __restrict__ out) {
    int c = threadIdx.x;
    int blk = blockIdx.x;
    int b = blk / 250;
    int t0 = (blk % 250) * 16;
    float p0 = probs[b * 2 + 0], p1 = probs[b * 2 + 1];
    float cw[39];
#pragma unroll
    for (int j = 0; j < 39; ++j) cw[j] = conv_w[c * 39 + j];
    float acc[16];
#pragma unroll
    for (int o = 0; o < 16; ++o) acc[o] = 0.f;
#pragma unroll
    for (int i = 0; i < 54; ++i) {
        int r = t0 - 19 + i;
        float v = 0.f;
        if (r >= 0 && r < NT) {
            size_t idx = ((size_t)b * NT + r) * OUT_CH + c;
            v = p0 * bf2f(mfull[idx]) + p1 * bf2f(msmall[idx]);
        }
#pragma unroll
        for (int o = 0; o < 16; ++o) {
            int j = i - o;                       // tap index (static after unroll)
            if (j >= 0 && j < 39) acc[o] += cw[j] * v;
            if (j == 19) acc[o] += v;            // identity (xp + conv)
        }
    }
#pragma unroll
    for (int o = 0; o < 16; ++o)
        out[((size_t)b * NT + t0 + o) * OUT_CH + c] = acc[o];
}

// ---------- launch ----------
extern "C" void kernel_launch(void* const* d_in, const int* in_sizes, int n_in,
                              void* d_out, int out_size, void* d_ws, size_t ws_size,
                              hipStream_t stream) {
    const float* x      = (const float*)d_in[0];
    const float* w1     = (const float*)d_in[1];
    const float* b1     = (const float*)d_in[2];
    const float* w2     = (const float*)d_in[3];
    const float* conv_w = (const float*)d_in[4];
    const float* gate_w = (const float*)d_in[5];
    const float* gate_b = (const float*)d_in[6];
    const float* tau    = (const float*)d_in[7];
    float* out = (float*)d_out;

    char* ws = (char*)d_ws;
    unsigned short* w1b    = (unsigned short*)(ws);
    unsigned short* w2b    = (unsigned short*)(ws + 1048576);
    unsigned short* msmall = (unsigned short*)(ws + 2097152);
    unsigned short* mfull  = (unsigned short*)(ws + 2097152 + 16384000);
    float* psum  = (float*)(ws + 2097152 + 2 * 16384000);
    float* psq   = psum + 256 * 256;
    float* probs = psq + 256 * 256;

    cvt_kernel<<<dim3(512), dim3(256), 0, stream>>>(w1, w1b, 131072);
    cvt_kernel<<<dim3(512), dim3(256), 0, stream>>>(w2, w2b, 131072);
    reduce_kernel<<<dim3(256), dim3(256), 0, stream>>>(x, psum, psq);
    gate_kernel<<<dim3(1), dim3(256), 0, stream>>>(psum, psq, gate_w, gate_b, tau,
                                                   probs, out + 8192000);
    gemm_kernel<<<dim3(500), dim3(512), 0, stream>>>(x, w1b, w2b, b1, msmall, mfull);
    conv_kernel<<<dim3(2000), dim3(256), 0, stream>>>(msmall, mfull, conv_w, probs, out);
}

// Round 2
// 244.221 us; speedup vs baseline: 1.3858x; 1.3858x over previous
//
#include <hip/hip_runtime.h>

// ---------- types ----------
typedef __bf16 bf16x8 __attribute__((ext_vector_type(8)));
typedef float  f32x4  __attribute__((ext_vector_type(4)));
typedef unsigned short u16x8 __attribute__((ext_vector_type(8)));

#define IN_CH  256
#define OUT_CH 256
#define HIDDEN 2048
#define NB     8
#define NT     4000
#define NROW   32000   // NB*NT

__device__ __forceinline__ unsigned short f2bf(float f) {
    unsigned u = __float_as_uint(f);
    u += 0x7FFFu + ((u >> 16) & 1u);           // round-to-nearest-even
    return (unsigned short)(u >> 16);
}
__device__ __forceinline__ float bf2f(unsigned short h) {
    return __uint_as_float(((unsigned)h) << 16);
}

// ---------- 1. fp32 -> bf16 convert (weights) ----------
__global__ void cvt_kernel(const float* __restrict__ in,
                           unsigned short* __restrict__ out, int n4) {
    int i = blockIdx.x * blockDim.x + threadIdx.x;
    if (i >= n4) return;
    float4 v = reinterpret_cast<const float4*>(in)[i];
    ushort4 o;
    o.x = f2bf(v.x); o.y = f2bf(v.y); o.z = f2bf(v.z); o.w = f2bf(v.w);
    reinterpret_cast<ushort4*>(out)[i] = o;
}

// ---------- 2. partial mean/var reduction over T ----------
__global__ void reduce_kernel(const float* __restrict__ x,
                              float* __restrict__ psum, float* __restrict__ psq) {
    int c = threadIdx.x;
    int blk = blockIdx.x;
    int b = blk >> 5, tc = blk & 31;
    const float* base = x + ((size_t)b * NT + tc * 125) * IN_CH + c;
    float s = 0.f, q = 0.f;
    for (int t = 0; t < 125; ++t) {
        float v = base[(size_t)t * IN_CH];
        s += v; q += v * v;
    }
    psum[blk * IN_CH + c] = s;
    psq [blk * IN_CH + c] = q;
}

// ---------- 3. gate: mean/std -> logits -> probs -> losses ----------
__global__ __launch_bounds__(256) void gate_kernel(
    const float* __restrict__ psum, const float* __restrict__ psq,
    const float* __restrict__ gate_w, const float* __restrict__ gate_b,
    const float* __restrict__ tau, float* __restrict__ probs,
    float* __restrict__ losses) {
    __shared__ float gi[NB][2 * IN_CH];
    __shared__ float lgt[16];
    int tid = threadIdx.x;
    for (int b = 0; b < NB; ++b) {
        float s = 0.f, q = 0.f;
        for (int p = 0; p < 32; ++p) {
            s += psum[(b * 32 + p) * IN_CH + tid];
            q += psq [(b * 32 + p) * IN_CH + tid];
        }
        float mean = s * (1.f / 4000.f);
        float var  = (q - s * s * (1.f / 4000.f)) * (1.f / 3999.f);  // ddof=1
        gi[b][tid]          = mean;
        gi[b][IN_CH + tid]  = sqrtf(fmaxf(var, 0.f));
    }
    __syncthreads();
    if (tid < 16) {
        int b = tid >> 1, k = tid & 1;
        float d = 0.f;
        for (int i = 0; i < 2 * IN_CH; ++i) d += gi[b][i] * gate_w[k * 2 * IN_CH + i];
        lgt[tid] = tau[0] * (d + gate_b[k]);
    }
    __syncthreads();
    if (tid == 0) {
        float pr[16];
        float i0 = 0.f, i1 = 0.f, sp = 0.f;
        for (int b = 0; b < NB; ++b) {
            float a = lgt[b * 2], c2 = lgt[b * 2 + 1];
            float mx = fmaxf(a, c2);
            float e0 = expf(a - mx), e1 = expf(c2 - mx);
            float inv = 1.f / (e0 + e1);
            float q0 = e0 * inv, q1 = e1 * inv;
            pr[b * 2] = q0; pr[b * 2 + 1] = q1;
            i0 += q0; i1 += q1;
            float nrm = sqrtf(q0 * q0 + q1 * q1) + 1e-8f;
            sp += (q0 + q1) / nrm;
        }
        losses[0] = 0.1f * sp * (1.f / 8.f);
        i0 *= (1.f / 8.f); i1 *= (1.f / 8.f);
        float meanI = 0.5f * (i0 + i1);
        float stdI  = fabsf(i0 - i1) * 0.7071067811865476f;
        float cv = stdI / (meanI + 1e-8f);
        losses[1] = 0.01f * cv * cv;
        for (int t = 0; t < 16; ++t) probs[t] = pr[t];
    }
}

// ---------- 4. fused GEMM1(relu)+GEMM2 with mid-loop small snapshot ----------
__global__ __launch_bounds__(512, 2) void gemm_kernel(
    const float* __restrict__ x,
    const unsigned short* __restrict__ w1b,   // [2048][256] bf16
    const unsigned short* __restrict__ w2b,   // [256][2048] bf16
    const float* __restrict__ b1,
    unsigned short* __restrict__ msmall,      // [32000][256] bf16
    unsigned short* __restrict__ mfull) {
    __shared__ __align__(16) unsigned short xt [64 * 256];
    __shared__ __align__(16) unsigned short w1c[64 * 256];
    __shared__ __align__(16) unsigned short w2c[256 * 64];
    __shared__ __align__(16) unsigned short f1t[64 * 72];

    const int tid   = threadIdx.x;
    const int lane  = tid & 63;
    const int wv    = tid >> 6;
    const int rband = wv & 3;
    const int chalf = wv >> 2;
    const int m0    = blockIdx.x * 64;
    const int l15   = lane & 15;
    const int lg    = lane >> 4;

#pragma unroll
    for (int p = 0; p < 8; ++p) {
        int E = p * 2048 + tid * 4;
        int r = E >> 8, c = E & 255;
        float4 v = *reinterpret_cast<const float4*>(x + (size_t)(m0 + r) * IN_CH + c);
        ushort4 h;
        h.x = f2bf(v.x); h.y = f2bf(v.y); h.z = f2bf(v.z); h.w = f2bf(v.w);
        *reinterpret_cast<ushort4*>(&xt[r * 256 + (c ^ ((r & 7) << 3))]) = h;
    }

    f32x4 acc2[8];
#pragma unroll
    for (int t = 0; t < 8; ++t) { acc2[t][0]=0.f; acc2[t][1]=0.f; acc2[t][2]=0.f; acc2[t][3]=0.f; }

    const int arow = rband * 16 + l15;

#pragma unroll 1
    for (int chunk = 0; chunk < 32; ++chunk) {
        const int h0 = chunk * 64;
#pragma unroll
        for (int p = 0; p < 4; ++p) {
            int E = p * 4096 + tid * 8;
            int r = E >> 8, c = E & 255;
            int4 v = *reinterpret_cast<const int4*>(w1b + (size_t)(h0 + r) * IN_CH + c);
            *reinterpret_cast<int4*>(&w1c[r * 256 + (c ^ ((r & 7) << 3))]) = v;
        }
#pragma unroll
        for (int p = 0; p < 4; ++p) {
            int E = p * 4096 + tid * 8;
            int r = E >> 6, c = E & 63;
            int4 v = *reinterpret_cast<const int4*>(w2b + (size_t)r * HIDDEN + h0 + c);
            *reinterpret_cast<int4*>(&w2c[r * 64 + (c ^ ((r & 7) << 3))]) = v;
        }
        __syncthreads();

        f32x4 acc1[2];
#pragma unroll
        for (int t = 0; t < 2; ++t) { acc1[t][0]=0.f; acc1[t][1]=0.f; acc1[t][2]=0.f; acc1[t][3]=0.f; }
#pragma unroll
        for (int kk = 0; kk < 8; ++kk) {
            int acol = kk * 32 + lg * 8;
            bf16x8 a = *reinterpret_cast<const bf16x8*>(
                &xt[arow * 256 + (acol ^ ((arow & 7) << 3))]);
#pragma unroll
            for (int t = 0; t < 2; ++t) {
                int hl = chalf * 32 + t * 16 + l15;
                bf16x8 bb = *reinterpret_cast<const bf16x8*>(
                    &w1c[hl * 256 + (acol ^ ((hl & 7) << 3))]);
                acc1[t] = __builtin_amdgcn_mfma_f32_16x16x32_bf16(a, bb, acc1[t], 0, 0, 0);
            }
        }
#pragma unroll
        for (int t = 0; t < 2; ++t) {
            int hl = chalf * 32 + t * 16 + l15;
            float bias = b1[h0 + hl];
#pragma unroll
            for (int r = 0; r < 4; ++r) {
                float v = fmaxf(acc1[t][r] + bias, 0.f);
                int rr = rband * 16 + lg * 4 + r;
                f1t[rr * 72 + hl] = f2bf(v);
            }
        }
        __syncthreads();

#pragma unroll
        for (int kk = 0; kk < 2; ++kk) {
            int kE = kk * 32 + lg * 8;
            bf16x8 a2 = *reinterpret_cast<const bf16x8*>(&f1t[arow * 72 + kE]);
#pragma unroll
            for (int t = 0; t < 8; ++t) {
                int oc = chalf * 128 + t * 16 + l15;
                bf16x8 b2 = *reinterpret_cast<const bf16x8*>(
                    &w2c[oc * 64 + (kE ^ ((oc & 7) << 3))]);
                acc2[t] = __builtin_amdgcn_mfma_f32_16x16x32_bf16(a2, b2, acc2[t], 0, 0, 0);
            }
        }

        if (chunk == 3) {
#pragma unroll
            for (int t = 0; t < 8; ++t) {
                int oc = chalf * 128 + t * 16 + l15;
#pragma unroll
                for (int r = 0; r < 4; ++r) {
                    int rr = m0 + rband * 16 + lg * 4 + r;
                    msmall[(size_t)rr * OUT_CH + oc] = f2bf(acc2[t][r]);
                }
            }
        }
        __syncthreads();
    }
#pragma unroll
    for (int t = 0; t < 8; ++t) {
        int oc = chalf * 128 + t * 16 + l15;
#pragma unroll
        for (int r = 0; r < 4; ++r) {
            int rr = m0 + rband * 16 + lg * 4 + r;
            mfull[(size_t)rr * OUT_CH + oc] = f2bf(acc2[t][r]);
        }
    }
}

// ---------- 5. mix + depthwise conv (39 taps) + identity, LDS-staged ----------
// grid 256 = 8 b x 32 t-tiles (128 t each); 512 threads.
// Phase 1: stage mixed = p0*full + p1*small (bf16) rows [t0-19, t0+146] into LDS.
// Phase 2: each thread = (channel c, t-half th), 8 groups of 8 outputs,
//          all register indices compile-time static (no scratch).
#define CTT 128                 // t outputs per block
#define CROWS (CTT + 38)        // 166 staged rows
__global__ __launch_bounds__(512) void conv_kernel(
    const unsigned short* __restrict__ msmall,
    const unsigned short* __restrict__ mfull,
    const float* __restrict__ conv_w,   // [256][1][39]
    const float* __restrict__ probs,    // [8][2]
    float* __restrict__ out) {
    __shared__ __align__(16) unsigned short mix[CROWS * 256];

    const int tid = threadIdx.x;
    const int blk = blockIdx.x;
    const int b   = blk >> 5;
    const int t0  = (blk & 31) * CTT;
    const float p0 = probs[b * 2 + 0], p1 = probs[b * 2 + 1];

    // ---- stage: 166*256/8 = 5312 ushort8 chunks, 512 threads ----
#pragma unroll
    for (int it = 0; it < 11; ++it) {
        int chunk = it * 512 + tid;
        if (it == 10 && tid >= 192) break;
        int e = chunk * 8;
        int s = e >> 8, c = e & 255;
        int t = t0 - 19 + s;
        u16x8 o;
        if (t >= 0 && t < NT) {
            size_t idx = ((size_t)b * NT + t) * OUT_CH + c;
            u16x8 vf = *reinterpret_cast<const u16x8*>(&mfull[idx]);
            u16x8 vs = *reinterpret_cast<const u16x8*>(&msmall[idx]);
#pragma unroll
            for (int k = 0; k < 8; ++k)
                o[k] = f2bf(p0 * bf2f(vf[k]) + p1 * bf2f(vs[k]));
        } else {
#pragma unroll
            for (int k = 0; k < 8; ++k) o[k] = 0;
        }
        *reinterpret_cast<u16x8*>(&mix[s * 256 + c]) = o;
    }
    __syncthreads();

    // ---- compute ----
    const int c  = tid & 255;
    const int th = tid >> 8;          // 0 or 1 -> t-half
    float cw[39];
#pragma unroll
    for (int j = 0; j < 39; ++j) cw[j] = conv_w[c * 39 + j];

#pragma unroll 1
    for (int g = 0; g < 8; ++g) {
        const int u0 = th * 64 + g * 8;   // output row offset in tile
        float vwin[46];
#pragma unroll
        for (int i = 0; i < 46; ++i)
            vwin[i] = bf2f(mix[(u0 + i) * 256 + c]);
        float acc[8];
#pragma unroll
        for (int o = 0; o < 8; ++o) {
            float a = vwin[o + 19];       // identity (xp + conv)
#pragma unroll
            for (int j = 0; j < 39; ++j)
                a += cw[j] * vwin[o + j];
            acc[o] = a;
        }
        const int tbase = t0 + u0;
#pragma unroll
        for (int o = 0; o < 8; ++o) {
            int t = tbase + o;
            if (t < NT)
                out[((size_t)b * NT + t) * OUT_CH + c] = acc[o];
        }
    }
}

// ---------- launch ----------
extern "C" void kernel_launch(void* const* d_in, const int* in_sizes, int n_in,
                              void* d_out, int out_size, void* d_ws, size_t ws_size,
                              hipStream_t stream) {
    const float* x      = (const float*)d_in[0];
    const float* w1     = (const float*)d_in[1];
    const float* b1     = (const float*)d_in[2];
    const float* w2     = (const float*)d_in[3];
    const float* conv_w = (const float*)d_in[4];
    const float* gate_w = (const float*)d_in[5];
    const float* gate_b = (const float*)d_in[6];
    const float* tau    = (const float*)d_in[7];
    float* out = (float*)d_out;

    char* ws = (char*)d_ws;
    unsigned short* w1b    = (unsigned short*)(ws);
    unsigned short* w2b    = (unsigned short*)(ws + 1048576);
    unsigned short* msmall = (unsigned short*)(ws + 2097152);
    unsigned short* mfull  = (unsigned short*)(ws + 2097152 + 16384000);
    float* psum  = (float*)(ws + 2097152 + 2 * 16384000);
    float* psq   = psum + 256 * 256;
    float* probs = psq + 256 * 256;

    cvt_kernel<<<dim3(512), dim3(256), 0, stream>>>(w1, w1b, 131072);
    cvt_kernel<<<dim3(512), dim3(256), 0, stream>>>(w2, w2b, 131072);
    reduce_kernel<<<dim3(256), dim3(256), 0, stream>>>(x, psum, psq);
    gate_kernel<<<dim3(1), dim3(256), 0, stream>>>(psum, psq, gate_w, gate_b, tau,
                                                   probs, out + 8192000);
    gemm_kernel<<<dim3(500), dim3(512), 0, stream>>>(x, w1b, w2b, b1, msmall, mfull);
    conv_kernel<<<dim3(256), dim3(512), 0, stream>>>(msmall, mfull, conv_w, probs, out);
}

// Round 3
// 176.646 us; speedup vs baseline: 1.9159x; 1.3825x over previous
//
#include <hip/hip_runtime.h>

// ---------- types ----------
typedef __bf16 bf16x8 __attribute__((ext_vector_type(8)));
typedef float  f32x4  __attribute__((ext_vector_type(4)));
typedef unsigned short u16x8 __attribute__((ext_vector_type(8)));

#define IN_CH  256
#define OUT_CH 256
#define HIDDEN 2048
#define NB     8
#define NT     4000
#define NROW   32000   // NB*NT

__device__ __forceinline__ unsigned short f2bf(float f) {
    unsigned u = __float_as_uint(f);
    u += 0x7FFFu + ((u >> 16) & 1u);           // round-to-nearest-even
    return (unsigned short)(u >> 16);
}
__device__ __forceinline__ float bf2f(unsigned short h) {
    return __uint_as_float(((unsigned)h) << 16);
}

#define GLOAD_LDS16(g, l) \
    __builtin_amdgcn_global_load_lds((const __attribute__((address_space(1))) void*)(g), \
                                     (__attribute__((address_space(3))) void*)(l), 16, 0, 0)

// ---------- 1. fp32 -> bf16 convert (weights) ----------
__global__ void cvt_kernel(const float* __restrict__ in,
                           unsigned short* __restrict__ out, int n4) {
    int i = blockIdx.x * blockDim.x + threadIdx.x;
    if (i >= n4) return;
    float4 v = reinterpret_cast<const float4*>(in)[i];
    ushort4 o;
    o.x = f2bf(v.x); o.y = f2bf(v.y); o.z = f2bf(v.z); o.w = f2bf(v.w);
    reinterpret_cast<ushort4*>(out)[i] = o;
}

// ---------- 2. partial mean/var reduction over T ----------
__global__ void reduce_kernel(const float* __restrict__ x,
                              float* __restrict__ psum, float* __restrict__ psq) {
    int c = threadIdx.x;
    int blk = blockIdx.x;
    int b = blk >> 5, tc = blk & 31;
    const float* base = x + ((size_t)b * NT + tc * 125) * IN_CH + c;
    float s = 0.f, q = 0.f;
    for (int t = 0; t < 125; ++t) {
        float v = base[(size_t)t * IN_CH];
        s += v; q += v * v;
    }
    psum[blk * IN_CH + c] = s;
    psq [blk * IN_CH + c] = q;
}

// ---------- 3. gate: mean/std -> logits -> probs -> losses ----------
__global__ __launch_bounds__(256) void gate_kernel(
    const float* __restrict__ psum, const float* __restrict__ psq,
    const float* __restrict__ gate_w, const float* __restrict__ gate_b,
    const float* __restrict__ tau, float* __restrict__ probs,
    float* __restrict__ losses) {
    __shared__ float gi[NB][2 * IN_CH];
    __shared__ float lgt[16];
    int tid = threadIdx.x;
    for (int b = 0; b < NB; ++b) {
        float s = 0.f, q = 0.f;
        for (int p = 0; p < 32; ++p) {
            s += psum[(b * 32 + p) * IN_CH + tid];
            q += psq [(b * 32 + p) * IN_CH + tid];
        }
        float mean = s * (1.f / 4000.f);
        float var  = (q - s * s * (1.f / 4000.f)) * (1.f / 3999.f);  // ddof=1
        gi[b][tid]          = mean;
        gi[b][IN_CH + tid]  = sqrtf(fmaxf(var, 0.f));
    }
    __syncthreads();
    if (tid < 16) {
        int b = tid >> 1, k = tid & 1;
        float d = 0.f;
        for (int i = 0; i < 2 * IN_CH; ++i) d += gi[b][i] * gate_w[k * 2 * IN_CH + i];
        lgt[tid] = tau[0] * (d + gate_b[k]);
    }
    __syncthreads();
    if (tid == 0) {
        float pr[16];
        float i0 = 0.f, i1 = 0.f, sp = 0.f;
        for (int b = 0; b < NB; ++b) {
            float a = lgt[b * 2], c2 = lgt[b * 2 + 1];
            float mx = fmaxf(a, c2);
            float e0 = expf(a - mx), e1 = expf(c2 - mx);
            float inv = 1.f / (e0 + e1);
            float q0 = e0 * inv, q1 = e1 * inv;
            pr[b * 2] = q0; pr[b * 2 + 1] = q1;
            i0 += q0; i1 += q1;
            float nrm = sqrtf(q0 * q0 + q1 * q1) + 1e-8f;
            sp += (q0 + q1) / nrm;
        }
        losses[0] = 0.1f * sp * (1.f / 8.f);
        i0 *= (1.f / 8.f); i1 *= (1.f / 8.f);
        float meanI = 0.5f * (i0 + i1);
        float stdI  = fabsf(i0 - i1) * 0.7071067811865476f;
        float cv = stdI / (meanI + 1e-8f);
        losses[1] = 0.01f * cv * cv;
        for (int t = 0; t < 16; ++t) probs[t] = pr[t];
    }
}

// ---------- 4. fused GEMM1(relu)+GEMM2, M=128, x in regs, dbuf weights ----------
// 250 blocks x 512 threads (8 waves = 4 rbands x 2 chalf).
// Per chunk (64 hidden): GEMM1 32 MFMA/wave, GEMM2 32 MFMA/wave, 2 barriers.
// Weights stream via global_load_lds (linear LDS dest, inverse-swizzled source).
__global__ __launch_bounds__(512, 2) void gemm_kernel(
    const float* __restrict__ x,
    const unsigned short* __restrict__ w1b,   // [2048][256] bf16
    const unsigned short* __restrict__ w2b,   // [256][2048] bf16
    const float* __restrict__ b1,
    unsigned short* __restrict__ msmall,      // [32000][256] bf16
    unsigned short* __restrict__ mfull) {
    __shared__ __align__(16) unsigned short w1c[2][64 * 256];   // 64 KB (dbuf)
    __shared__ __align__(16) unsigned short w2c[2][256 * 64];   // 64 KB (dbuf)
    __shared__ __align__(16) unsigned short f1t[128 * 72];      // 18 KB
    __shared__ float b1s[HIDDEN];                               // 8 KB

    const int tid   = threadIdx.x;
    const int lane  = tid & 63;
    const int wv    = tid >> 6;       // 0..7
    const int rband = wv & 3;         // 32-row band
    const int chalf = wv >> 2;        // 0..1
    const int m0    = blockIdx.x * 128;
    const int l15   = lane & 15;
    const int lg    = lane >> 4;      // 0..3

    // ---- stage chunk 0 weights (buf 0) ----
    {
        const unsigned short* w1s = w1b;            // h0 = 0
        const unsigned short* w2s = w2b;
#pragma unroll
        for (int i = 0; i < 4; ++i) {
            int r1 = (wv * 4 + i) * 2 + (lane >> 5);
            int c1 = ((lane & 31) * 8) ^ ((r1 & 7) << 3);
            GLOAD_LDS16(w1s + r1 * 256 + c1, &w1c[0][(wv * 4 + i) * 512]);
            int r2 = (wv * 4 + i) * 8 + (lane >> 3);
            int c2 = ((lane & 7) * 8) ^ ((r2 & 7) << 3);
            GLOAD_LDS16(w2s + (size_t)r2 * HIDDEN + c2, &w2c[0][(wv * 4 + i) * 512]);
        }
    }
    // ---- bias to LDS ----
#pragma unroll
    for (int p = 0; p < 4; ++p) b1s[p * 512 + tid] = b1[p * 512 + tid];

    // ---- x fragments to registers: xr[rt][kk], rows rband*32+rt*16+l15 ----
    bf16x8 xr[2][8];
#pragma unroll
    for (int rt = 0; rt < 2; ++rt) {
        const float* xrow = x + (size_t)(m0 + rband * 32 + rt * 16 + l15) * IN_CH;
#pragma unroll
        for (int kk = 0; kk < 8; ++kk) {
            float4 v0 = *reinterpret_cast<const float4*>(xrow + kk * 32 + lg * 8);
            float4 v1 = *reinterpret_cast<const float4*>(xrow + kk * 32 + lg * 8 + 4);
            bf16x8 h;
            h[0] = (__bf16)v0.x; h[1] = (__bf16)v0.y; h[2] = (__bf16)v0.z; h[3] = (__bf16)v0.w;
            h[4] = (__bf16)v1.x; h[5] = (__bf16)v1.y; h[6] = (__bf16)v1.z; h[7] = (__bf16)v1.w;
            xr[rt][kk] = h;
        }
    }

    f32x4 acc2[2][8];
#pragma unroll
    for (int rt = 0; rt < 2; ++rt)
#pragma unroll
        for (int t = 0; t < 8; ++t) { acc2[rt][t][0]=0.f; acc2[rt][t][1]=0.f; acc2[rt][t][2]=0.f; acc2[rt][t][3]=0.f; }

    __syncthreads();   // chunk-0 staging (vmcnt drained) + b1s ready

#pragma unroll 1
    for (int chunk = 0; chunk < 32; ++chunk) {
        const int buf = chunk & 1;
        // ---- issue next chunk's staging into buf^1 ----
        if (chunk < 31) {
            const int h0n = (chunk + 1) * 64;
            const unsigned short* w1s = w1b + (size_t)h0n * IN_CH;
            const unsigned short* w2s = w2b + h0n;
#pragma unroll
            for (int i = 0; i < 4; ++i) {
                int r1 = (wv * 4 + i) * 2 + (lane >> 5);
                int c1 = ((lane & 31) * 8) ^ ((r1 & 7) << 3);
                GLOAD_LDS16(w1s + r1 * 256 + c1, &w1c[buf ^ 1][(wv * 4 + i) * 512]);
                int r2 = (wv * 4 + i) * 8 + (lane >> 3);
                int c2 = ((lane & 7) * 8) ^ ((r2 & 7) << 3);
                GLOAD_LDS16(w2s + (size_t)r2 * HIDDEN + c2, &w2c[buf ^ 1][(wv * 4 + i) * 512]);
            }
        }

        const unsigned short* W1 = w1c[buf];
        const unsigned short* W2 = w2c[buf];

        // ---- GEMM1: f1[128][64] = relu(x @ w1_chunk^T + b1) ----
        f32x4 acc1[2][2];
#pragma unroll
        for (int rt = 0; rt < 2; ++rt)
#pragma unroll
            for (int t = 0; t < 2; ++t) { acc1[rt][t][0]=0.f; acc1[rt][t][1]=0.f; acc1[rt][t][2]=0.f; acc1[rt][t][3]=0.f; }
#pragma unroll
        for (int kk = 0; kk < 8; ++kk) {
            const int kE = kk * 32 + lg * 8;
            bf16x8 bb[2];
#pragma unroll
            for (int t = 0; t < 2; ++t) {
                int hl = chalf * 32 + t * 16 + l15;
                bb[t] = *reinterpret_cast<const bf16x8*>(
                    &W1[hl * 256 + (kE ^ ((hl & 7) << 3))]);
            }
#pragma unroll
            for (int rt = 0; rt < 2; ++rt)
#pragma unroll
                for (int t = 0; t < 2; ++t)
                    acc1[rt][t] = __builtin_amdgcn_mfma_f32_16x16x32_bf16(
                        xr[rt][kk], bb[t], acc1[rt][t], 0, 0, 0);
        }
        // bias + relu -> f1t
#pragma unroll
        for (int t = 0; t < 2; ++t) {
            int hl = chalf * 32 + t * 16 + l15;
            float bias = b1s[chunk * 64 + hl];
#pragma unroll
            for (int rt = 0; rt < 2; ++rt)
#pragma unroll
                for (int r = 0; r < 4; ++r) {
                    float v = fmaxf(acc1[rt][t][r] + bias, 0.f);
                    int rr = rband * 32 + rt * 16 + lg * 4 + r;
                    f1t[rr * 72 + hl] = f2bf(v);
                }
        }
        __syncthreads();

        // ---- GEMM2: acc2 += f1 @ w2_chunk^T ----
#pragma unroll
        for (int kk = 0; kk < 2; ++kk) {
            const int kE = kk * 32 + lg * 8;
            bf16x8 a2[2];
#pragma unroll
            for (int rt = 0; rt < 2; ++rt)
                a2[rt] = *reinterpret_cast<const bf16x8*>(
                    &f1t[(rband * 32 + rt * 16 + l15) * 72 + kE]);
#pragma unroll
            for (int t = 0; t < 8; ++t) {
                int oc = chalf * 128 + t * 16 + l15;
                bf16x8 b2 = *reinterpret_cast<const bf16x8*>(
                    &W2[oc * 64 + (kE ^ ((oc & 7) << 3))]);
#pragma unroll
                for (int rt = 0; rt < 2; ++rt)
                    acc2[rt][t] = __builtin_amdgcn_mfma_f32_16x16x32_bf16(
                        a2[rt], b2, acc2[rt][t], 0, 0, 0);
            }
        }

        if (chunk == 3) {   // hidden 0..255 done -> p1_small snapshot
#pragma unroll
            for (int t = 0; t < 8; ++t) {
                int oc = chalf * 128 + t * 16 + l15;
#pragma unroll
                for (int rt = 0; rt < 2; ++rt)
#pragma unroll
                    for (int r = 0; r < 4; ++r) {
                        int rr = m0 + rband * 32 + rt * 16 + lg * 4 + r;
                        msmall[(size_t)rr * OUT_CH + oc] = f2bf(acc2[rt][t][r]);
                    }
            }
        }
        __syncthreads();   // all reads of buf + f1t done; buf^1 staged (vmcnt drain)
    }
    // final: p1_full
#pragma unroll
    for (int t = 0; t < 8; ++t) {
        int oc = chalf * 128 + t * 16 + l15;
#pragma unroll
        for (int rt = 0; rt < 2; ++rt)
#pragma unroll
            for (int r = 0; r < 4; ++r) {
                int rr = m0 + rband * 32 + rt * 16 + lg * 4 + r;
                mfull[(size_t)rr * OUT_CH + oc] = f2bf(acc2[rt][t][r]);
            }
    }
}

// ---------- 5. mix + depthwise conv (39 taps) + identity, LDS-staged ----------
#define CTT 128                 // t outputs per block
#define CROWS (CTT + 38)        // 166 staged rows
__global__ __launch_bounds__(512) void conv_kernel(
    const unsigned short* __restrict__ msmall,
    const unsigned short* __restrict__ mfull,
    const float* __restrict__ conv_w,   // [256][1][39]
    const float* __restrict__ probs,    // [8][2]
    float* __restrict__ out) {
    __shared__ __align__(16) unsigned short mix[CROWS * 256];

    const int tid = threadIdx.x;
    const int blk = blockIdx.x;
    const int b   = blk >> 5;
    const int t0  = (blk & 31) * CTT;
    const float p0 = probs[b * 2 + 0], p1 = probs[b * 2 + 1];

#pragma unroll
    for (int it = 0; it < 11; ++it) {
        int chunk = it * 512 + tid;
        if (it == 10 && tid >= 192) break;
        int e = chunk * 8;
        int s = e >> 8, c = e & 255;
        int t = t0 - 19 + s;
        u16x8 o;
        if (t >= 0 && t < NT) {
            size_t idx = ((size_t)b * NT + t) * OUT_CH + c;
            u16x8 vf = *reinterpret_cast<const u16x8*>(&mfull[idx]);
            u16x8 vs = *reinterpret_cast<const u16x8*>(&msmall[idx]);
#pragma unroll
            for (int k = 0; k < 8; ++k)
                o[k] = f2bf(p0 * bf2f(vf[k]) + p1 * bf2f(vs[k]));
        } else {
#pragma unroll
            for (int k = 0; k < 8; ++k) o[k] = 0;
        }
        *reinterpret_cast<u16x8*>(&mix[s * 256 + c]) = o;
    }
    __syncthreads();

    const int c  = tid & 255;
    const int th = tid >> 8;
    float cw[39];
#pragma unroll
    for (int j = 0; j < 39; ++j) cw[j] = conv_w[c * 39 + j];

#pragma unroll 1
    for (int g = 0; g < 8; ++g) {
        const int u0 = th * 64 + g * 8;
        float vwin[46];
#pragma unroll
        for (int i = 0; i < 46; ++i)
            vwin[i] = bf2f(mix[(u0 + i) * 256 + c]);
        float acc[8];
#pragma unroll
        for (int o = 0; o < 8; ++o) {
            float a = vwin[o + 19];
#pragma unroll
            for (int j = 0; j < 39; ++j)
                a += cw[j] * vwin[o + j];
            acc[o] = a;
        }
        const int tbase = t0 + u0;
#pragma unroll
        for (int o = 0; o < 8; ++o) {
            int t = tbase + o;
            if (t < NT)
                out[((size_t)b * NT + t) * OUT_CH + c] = acc[o];
        }
    }
}

// ---------- launch ----------
extern "C" void kernel_launch(void* const* d_in, const int* in_sizes, int n_in,
                              void* d_out, int out_size, void* d_ws, size_t ws_size,
                              hipStream_t stream) {
    const float* x      = (const float*)d_in[0];
    const float* w1     = (const float*)d_in[1];
    const float* b1     = (const float*)d_in[2];
    const float* w2     = (const float*)d_in[3];
    const float* conv_w = (const float*)d_in[4];
    const float* gate_w = (const float*)d_in[5];
    const float* gate_b = (const float*)d_in[6];
    const float* tau    = (const float*)d_in[7];
    float* out = (float*)d_out;

    char* ws = (char*)d_ws;
    unsigned short* w1b    = (unsigned short*)(ws);
    unsigned short* w2b    = (unsigned short*)(ws + 1048576);
    unsigned short* msmall = (unsigned short*)(ws + 2097152);
    unsigned short* mfull  = (unsigned short*)(ws + 2097152 + 16384000);
    float* psum  = (float*)(ws + 2097152 + 2 * 16384000);
    float* psq   = psum + 256 * 256;
    float* probs = psq + 256 * 256;

    cvt_kernel<<<dim3(512), dim3(256), 0, stream>>>(w1, w1b, 131072);
    cvt_kernel<<<dim3(512), dim3(256), 0, stream>>>(w2, w2b, 131072);
    reduce_kernel<<<dim3(256), dim3(256), 0, stream>>>(x, psum, psq);
    gate_kernel<<<dim3(1), dim3(256), 0, stream>>>(psum, psq, gate_w, gate_b, tau,
                                                   probs, out + 8192000);
    gemm_kernel<<<dim3(250), dim3(512), 0, stream>>>(x, w1b, w2b, b1, msmall, mfull);
    conv_kernel<<<dim3(256), dim3(512), 0, stream>>>(msmall, mfull, conv_w, probs, out);
}